// Round 7
// baseline (421.639 us; speedup 1.0000x reference)
//
#include <hip/hip_runtime.h>
#include <hip/hip_bf16.h>

typedef unsigned short u16;
typedef __attribute__((ext_vector_type(8))) __bf16 bf16x8;
typedef __attribute__((ext_vector_type(8))) u16 u16x8;
typedef __attribute__((ext_vector_type(4))) float f32x4;

__device__ __forceinline__ u16 f2bf(float f) {
    unsigned u = __float_as_uint(f);
    u += 0x7fffu + ((u >> 16) & 1u);   // round-to-nearest-even
    return (u16)(u >> 16);
}

__device__ __forceinline__ void gl_lds16(const void* g, void* l) {
    // direct global->LDS DMA, 16B/lane; LDS dest = wave-uniform base + lane*16
    __builtin_amdgcn_global_load_lds(
        (const __attribute__((address_space(1))) void*)g,
        (__attribute__((address_space(3))) void*)l, 16, 0, 0);
}

// ---------- kernel 0: W1 [4][256][128] fp32 -> W1T [4][128][256] bf16 ----------
__global__ __launch_bounds__(256) void transpose_w1(const float* __restrict__ W1,
                                                    u16* __restrict__ W1T) {
    __shared__ u16 tile[64][132];   // 64 d x 128 k, pad to 132
    const int t = threadIdx.x;
    const int h = blockIdx.x >> 2;
    const int dt = blockIdx.x & 3;
#pragma unroll
    for (int j = 0; j < 8; ++j) {
        int idx = j * 256 + t;          // 2048 float4 slots
        int r = idx >> 5;               // d-row 0..63
        int kq = idx & 31;              // float4 col
        float4 v = *reinterpret_cast<const float4*>(
            W1 + ((size_t)h * 256 + dt * 64 + r) * 128 + kq * 4);
        ushort4 o;
        o.x = f2bf(v.x); o.y = f2bf(v.y); o.z = f2bf(v.z); o.w = f2bf(v.w);
        *reinterpret_cast<ushort4*>(&tile[r][kq * 4]) = o;
    }
    __syncthreads();
#pragma unroll
    for (int j = 0; j < 4; ++j) {
        int idx = j * 256 + t;          // 1024 u16x8 slots
        int k = idx >> 3;               // 0..127
        int c8 = idx & 7;
        u16x8 o;
#pragma unroll
        for (int e = 0; e < 8; ++e) o[e] = tile[c8 * 8 + e][k];
        *reinterpret_cast<u16x8*>(W1T + ((size_t)h * 128 + k) * 256 + dt * 64 + c8 * 8) = o;
    }
}

// ---------- kernel 1: scores[N][4] = relu(x*W1+b1)*W2 + b2 ----------
// 512 threads = 8 waves; wave w -> head hh = w>>1, row-half = w&1 (64 rows).
// Same verified layouts as r6 (which passed): xb reader-linear + XOR swizzle,
// sA staged by pre-swizzled-source global_load_lds, lane-linear reads.
// 16 waves/CU (2 blocks x 8 waves) vs r6's 8: double the latency-hiding.
// Cross-half score reduce via 1KB LDS at the end.
__global__ __launch_bounds__(512, 4) void score_kernel(
        const float* __restrict__ x, const u16* __restrict__ W1T,
        const float* __restrict__ b1, const float* __restrict__ W2,
        const float* __restrict__ b2, float* __restrict__ scores, int N) {
    __shared__ u16 xb[16384];       // [ks][nf][slot q][8 bf16] = 32 KB
    __shared__ u16 sA[16384];       // [w*4+j][slot][8 bf16]    = 32 KB
    __shared__ float pr[4][4][16];  // cross-half partials        = 1 KB

    const int t = threadIdx.x;
    const int wave = t >> 6;        // 0..7
    const int lane = t & 63;
    const int l15 = lane & 15;
    const int quad = lane >> 4;
    const int hh = wave >> 1;       // head 0..3
    const int half = wave & 1;      // row half 0..1
    const int n0 = blockIdx.x * 64;

    // ---- pre-swizzled A source: DMA slot s gets reader-lane s's frag
    //      (row = base + s&15, kc = (s>>4)*8). per j: +j*4096; per ks: +ks*32.
    const u16* asrc = W1T + ((size_t)hh * 128 + half * 64 + l15) * 256 + quad * 8;
    auto stageA = [&](int ks) {
#pragma unroll
        for (int j = 0; j < 4; ++j)
            gl_lds16(asrc + j * 4096 + ks * 32, &sA[(size_t)(wave * 4 + j) * 512]);
    };
    stageA(0);      // DMA overlaps x staging

    // ---- stage x: thread t -> node n = t>>3, k-step ks = t&7 (32 k, 128B).
    //      4 quads -> slots l = kcq*16 + (n&15), q = l ^ (kcq<<1).
    {
        const int n = t >> 3;
        const int ks = t & 7;
        int nn = n0 + n; if (nn >= N) nn = N - 1;   // clamp (never hits: N%64==0)
        const float* src = x + (size_t)nn * 256 + ks * 32;
        float4 v[8];
#pragma unroll
        for (int i = 0; i < 8; ++i)
            v[i] = *reinterpret_cast<const float4*>(src + i * 4);
        const int nf = n >> 4;
        const int r15 = n & 15;
#pragma unroll
        for (int kcq = 0; kcq < 4; ++kcq) {
            const int q = (kcq * 16 + r15) ^ (kcq << 1);
            u16x8 o;
            float4 vA = v[2 * kcq], vB = v[2 * kcq + 1];
            o[0] = f2bf(vA.x); o[1] = f2bf(vA.y); o[2] = f2bf(vA.z); o[3] = f2bf(vA.w);
            o[4] = f2bf(vB.x); o[5] = f2bf(vB.y); o[6] = f2bf(vB.z); o[7] = f2bf(vB.w);
            *reinterpret_cast<u16x8*>(&xb[((ks * 4 + nf) * 64 + q) * 8]) = o;
        }
    }

    const int qr = lane ^ ((lane >> 4) << 1);
    const u16* xrd = xb + qr * 8;
    const u16* abase = &sA[(size_t)wave * 2048 + lane * 8];

    __syncthreads();    // xb + sA(0) staged

    f32x4 acc[4][4] = {};
    for (int ks = 0; ks < 8; ++ks) {
        bf16x8 a[4], b[4];
#pragma unroll
        for (int j = 0; j < 4; ++j)
            a[j] = *reinterpret_cast<const bf16x8*>(abase + j * 512);
#pragma unroll
        for (int nf = 0; nf < 4; ++nf)
            b[nf] = *reinterpret_cast<const bf16x8*>(xrd + (ks * 4 + nf) * 512);
        __syncthreads();                    // all waves done reading sA[ks]
        if (ks < 7) stageA(ks + 1);         // async overwrite while MFMA runs
#pragma unroll
        for (int fr = 0; fr < 4; ++fr)
#pragma unroll
            for (int nf = 0; nf < 4; ++nf)
                acc[fr][nf] = __builtin_amdgcn_mfma_f32_16x16x32_bf16(
                    a[fr], b[nf], acc[fr][nf], 0, 0, 0);
        __syncthreads();                    // vmcnt(0) drain: staging complete
    }

    // ---- epilogue: partial score over this wave's 64 rows ----
    float4 b1v[4], w2v[4];
#pragma unroll
    for (int fr = 0; fr < 4; ++fr) {
        int rb = hh * 128 + half * 64 + fr * 16 + quad * 4;
        b1v[fr] = *reinterpret_cast<const float4*>(b1 + rb);
        w2v[fr] = *reinterpret_cast<const float4*>(W2 + rb);
    }
    float p[4];
#pragma unroll
    for (int nf = 0; nf < 4; ++nf) {
        float pp = 0.f;
#pragma unroll
        for (int fr = 0; fr < 4; ++fr) {
            f32x4 c = acc[fr][nf];
            pp += fmaxf(c[0] + b1v[fr].x, 0.f) * w2v[fr].x
                + fmaxf(c[1] + b1v[fr].y, 0.f) * w2v[fr].y
                + fmaxf(c[2] + b1v[fr].z, 0.f) * w2v[fr].z
                + fmaxf(c[3] + b1v[fr].w, 0.f) * w2v[fr].w;
        }
        pp += __shfl_xor(pp, 16, 64);
        pp += __shfl_xor(pp, 32, 64);
        p[nf] = pp;
    }
    if (half == 1 && lane < 16) {
#pragma unroll
        for (int nf = 0; nf < 4; ++nf) pr[hh][nf][lane] = p[nf];
    }
    __syncthreads();
    if (half == 0 && lane < 16) {
        const float b2v = b2[hh];
#pragma unroll
        for (int nf = 0; nf < 4; ++nf) {
            int n = n0 + nf * 16 + lane;
            if (n < N)
                scores[(size_t)n * 4 + hh] = p[nf] + pr[hh][nf][lane] + b2v;
        }
    }
}

// ---------- kernel 2: starts[g] = lower_bound(seg, g), g = 0..G ----------
__device__ __forceinline__ int lower_bound(const int* __restrict__ a, int n, int v) {
    int lo = 0, hi = n;
    while (lo < hi) {
        int mid = (lo + hi) >> 1;
        if (a[mid] < v) lo = mid + 1; else hi = mid;
    }
    return lo;
}

__global__ __launch_bounds__(256) void starts_kernel(
        const int* __restrict__ seg, int* __restrict__ starts, int N, int G) {
    int g = blockIdx.x * 256 + threadIdx.x;
    if (g > G) return;
    if (g == 0)      starts[0] = 0;
    else if (g == G) starts[G] = N;
    else             starts[g] = lower_bound(seg, N, g);
}

// ---------- kernel 3: fused per-graph softmax + weighted sum ----------
// 512 threads = 8 waves. Passes 1/2: per-head max / sum(exp) (block reduce).
// Pass 3: weights precomputed per 1024-node chunk into LDS (one barrier),
// then uninterrupted 8-deep-unrolled weighted sum; 2 threads per d-column
// (odd/even 8-node stripes), combined via LDS at the end. No atomics/memset.
__global__ __launch_bounds__(512) void pool_kernel(
        const float* __restrict__ x, const float4* __restrict__ scores4,
        const int* __restrict__ starts, float* __restrict__ out) {
    __shared__ float4 red[8];
    __shared__ float wl[1024];
    __shared__ float partial[512];
    const int g = blockIdx.x;
    const int t = threadIdx.x;
    const int lane = t & 63;
    const int wv = t >> 6;
    const int start = starts[g];
    const int end = starts[g + 1];
    const int len = end - start;

    float* og = out + (size_t)g * 256;
    if (len == 0) { if (t < 256) og[t] = 0.f; return; }   // uniform across block

    // ---- pass 1: per-head max ----
    float4 mx = make_float4(-3.4e38f, -3.4e38f, -3.4e38f, -3.4e38f);
    for (int i = start + t; i < end; i += 512) {
        float4 s = scores4[i];
        mx.x = fmaxf(mx.x, s.x); mx.y = fmaxf(mx.y, s.y);
        mx.z = fmaxf(mx.z, s.z); mx.w = fmaxf(mx.w, s.w);
    }
#pragma unroll
    for (int off = 1; off < 64; off <<= 1) {
        mx.x = fmaxf(mx.x, __shfl_xor(mx.x, off, 64));
        mx.y = fmaxf(mx.y, __shfl_xor(mx.y, off, 64));
        mx.z = fmaxf(mx.z, __shfl_xor(mx.z, off, 64));
        mx.w = fmaxf(mx.w, __shfl_xor(mx.w, off, 64));
    }
    if (lane == 0) red[wv] = mx;
    __syncthreads();
#pragma unroll
    for (int w = 1; w < 8; ++w) {
        mx.x = fmaxf(red[0].x, red[w].x) > mx.x ? fmaxf(red[0].x, red[w].x) : mx.x;
    }
    {
        float4 r = red[0];
        mx = r;
#pragma unroll
        for (int w = 1; w < 8; ++w) {
            float4 q = red[w];
            mx.x = fmaxf(mx.x, q.x); mx.y = fmaxf(mx.y, q.y);
            mx.z = fmaxf(mx.z, q.z); mx.w = fmaxf(mx.w, q.w);
        }
    }
    __syncthreads();    // red reuse

    // ---- pass 2: per-head sum(exp) ----
    float4 sm = make_float4(0.f, 0.f, 0.f, 0.f);
    for (int i = start + t; i < end; i += 512) {
        float4 s = scores4[i];
        sm.x += expf(s.x - mx.x); sm.y += expf(s.y - mx.y);
        sm.z += expf(s.z - mx.z); sm.w += expf(s.w - mx.w);
    }
#pragma unroll
    for (int off = 1; off < 64; off <<= 1) {
        sm.x += __shfl_xor(sm.x, off, 64);
        sm.y += __shfl_xor(sm.y, off, 64);
        sm.z += __shfl_xor(sm.z, off, 64);
        sm.w += __shfl_xor(sm.w, off, 64);
    }
    if (lane == 0) red[wv] = sm;
    __syncthreads();
    float4 inv;
    {
        float4 s0 = red[0];
#pragma unroll
        for (int w = 1; w < 8; ++w) {
            float4 q = red[w];
            s0.x += q.x; s0.y += q.y; s0.z += q.z; s0.w += q.w;
        }
        // max element contributes exp(0)=1 -> sums strictly positive
        inv.x = 1.f / s0.x; inv.y = 1.f / s0.y;
        inv.z = 1.f / s0.z; inv.w = 1.f / s0.w;
    }

    // ---- pass 3: chunked weights + weighted sum; 2 threads per column ----
    const int col = t & 255;
    const int hf = t >> 8;          // 0: even 8-stripes, 1: odd 8-stripes
    float acc = 0.f;
    for (int c = 0; c < len; c += 1024) {
        const int cl = min(1024, len - c);
        __syncthreads();            // previous chunk's wl readers done
        for (int i = t; i < cl; i += 512) {
            float4 s = scores4[start + c + i];
            wl[i] = 0.25f * (expf(s.x - mx.x) * inv.x + expf(s.y - mx.y) * inv.y +
                             expf(s.z - mx.z) * inv.z + expf(s.w - mx.w) * inv.w);
        }
        __syncthreads();
        const float* xp = x + (size_t)(start + c) * 256 + col;
        int jb = hf * 8;
        for (; jb + 8 <= cl; jb += 16) {
            float xv[8];
#pragma unroll
            for (int jj = 0; jj < 8; ++jj) xv[jj] = xp[(size_t)(jb + jj) * 256];
#pragma unroll
            for (int jj = 0; jj < 8; ++jj) acc += wl[jb + jj] * xv[jj];
        }
        if (jb < cl) {
            const int je = min(jb + 8, cl);
            for (int j = jb; j < je; ++j) acc += wl[j] * xp[(size_t)j * 256];
        }
    }
    partial[t] = acc;
    __syncthreads();
    if (t < 256) og[t] = partial[t] + partial[t + 256];
}

extern "C" void kernel_launch(void* const* d_in, const int* in_sizes, int n_in,
                              void* d_out, int out_size, void* d_ws, size_t ws_size,
                              hipStream_t stream) {
    const float* x  = (const float*)d_in[0];
    const int* seg  = (const int*)d_in[1];
    // d_in[2] = num_graphs scalar (G=1024, fixed by problem)
    const float* W1 = (const float*)d_in[3];
    const float* b1 = (const float*)d_in[4];
    const float* W2 = (const float*)d_in[5];
    const float* b2 = (const float*)d_in[6];
    float* out = (float*)d_out;

    const int N = in_sizes[0] / 256;     // 200000
    const int G = 1024;

    char* ws = (char*)d_ws;
    float* scores = (float*)ws;                                  // N*4 fp32 = 3.2 MB
    u16* W1T      = (u16*)(ws + (size_t)N * 16);                 // 131072 u16 = 256 KB
    int* starts   = (int*)(ws + (size_t)N * 16 + 262144);        // (G+1) int

    transpose_w1<<<16, 256, 0, stream>>>(W1, W1T);
    starts_kernel<<<(G + 256) / 256, 256, 0, stream>>>(seg, starts, N, G);
    score_kernel<<<(N + 63) / 64, 512, 0, stream>>>(x, W1T, b1, W2, b2, scores, N);
    pool_kernel<<<G, 512, 0, stream>>>(x, (const float4*)scores, starts, out);
}

// Round 8
// 393.517 us; speedup vs baseline: 1.0715x; 1.0715x over previous
//
#include <hip/hip_runtime.h>
#include <hip/hip_bf16.h>

typedef unsigned short u16;
typedef __attribute__((ext_vector_type(8))) __bf16 bf16x8;
typedef __attribute__((ext_vector_type(8))) u16 u16x8;
typedef __attribute__((ext_vector_type(4))) float f32x4;

__device__ __forceinline__ u16 f2bf(float f) {
    unsigned u = __float_as_uint(f);
    u += 0x7fffu + ((u >> 16) & 1u);   // round-to-nearest-even
    return (u16)(u >> 16);
}

// ---------- kernel 0: W1 [4][256][128] fp32 -> W1T [4][128][256] bf16 ----------
__global__ __launch_bounds__(256) void transpose_w1(const float* __restrict__ W1,
                                                    u16* __restrict__ W1T) {
    __shared__ u16 tile[64][132];   // 64 d x 128 k, pad to 132
    const int t = threadIdx.x;
    const int h = blockIdx.x >> 2;
    const int dt = blockIdx.x & 3;
#pragma unroll
    for (int j = 0; j < 8; ++j) {
        int idx = j * 256 + t;          // 2048 float4 slots
        int r = idx >> 5;               // d-row 0..63
        int kq = idx & 31;              // float4 col
        float4 v = *reinterpret_cast<const float4*>(
            W1 + ((size_t)h * 256 + dt * 64 + r) * 128 + kq * 4);
        ushort4 o;
        o.x = f2bf(v.x); o.y = f2bf(v.y); o.z = f2bf(v.z); o.w = f2bf(v.w);
        *reinterpret_cast<ushort4*>(&tile[r][kq * 4]) = o;
    }
    __syncthreads();
#pragma unroll
    for (int j = 0; j < 4; ++j) {
        int idx = j * 256 + t;          // 1024 u16x8 slots
        int k = idx >> 3;               // 0..127
        int c8 = idx & 7;
        u16x8 o;
#pragma unroll
        for (int e = 0; e < 8; ++e) o[e] = tile[c8 * 8 + e][k];
        *reinterpret_cast<u16x8*>(W1T + ((size_t)h * 128 + k) * 256 + dt * 64 + c8 * 8) = o;
    }
}

// ---------- kernel 1: scores[N][4] = relu(x*W1+b1)*W2 + b2 ----------
// Block = head h x 512-node chunk, 256 thr = 4 waves. Wave w owns W-rows
// w*32..w*32+31 of head h with A-frags RESIDENT IN REGISTERS (64 VGPR,
// loaded once) -- no W staging, no per-k-step barriers. Per 64-node tile:
// x f32->bf16 into double-buffered xb (verified r6 layout), pure k-loop
// {4 ds_read_b128 + 8 MFMA} x 8, partial epilogue per wave, cross-wave
// reduce via double-buffered pr. 2 barriers per tile. Next tile's global
// loads issued before the k-loop (latency hides under MFMA).
__global__ __launch_bounds__(256, 2) void score_kernel(
        const float* __restrict__ x, const u16* __restrict__ W1T,
        const float* __restrict__ b1, const float* __restrict__ W2,
        const float* __restrict__ b2, float* __restrict__ scores, int N) {
    __shared__ u16 xb[2][16384];        // 2 x [ks][nf][slot q][8 bf16] = 64 KB
    __shared__ float pr[2][4][4][16];   // [buf][src wave][nf][node]    = 512 B

    const int t = threadIdx.x;
    const int wave = t >> 6;
    const int lane = t & 63;
    const int l15 = lane & 15;
    const int quad = lane >> 4;
    const int h = blockIdx.x & 3;
    const int c0 = (blockIdx.x >> 2) * 512;

    // ---- resident A-frags: row = h*128 + wave*32 + fr*16 + l15,
    //      d-chunk = ks*32 + quad*8 (MFMA A layout, verified r2-r7)
    bf16x8 a[2][8];
    {
        const u16* ab = W1T + ((size_t)h * 128 + wave * 32 + l15) * 256 + quad * 8;
#pragma unroll
        for (int fr = 0; fr < 2; ++fr)
#pragma unroll
            for (int ks = 0; ks < 8; ++ks)
                a[fr][ks] = *reinterpret_cast<const bf16x8*>(ab + fr * 4096 + ks * 32);
    }
    float4 b1v[2], w2v[2];
#pragma unroll
    for (int fr = 0; fr < 2; ++fr) {
        int rb = h * 128 + wave * 32 + fr * 16 + quad * 4;
        b1v[fr] = *reinterpret_cast<const float4*>(b1 + rb);
        w2v[fr] = *reinterpret_cast<const float4*>(W2 + rb);
    }
    const float b2v = b2[h];

    // ---- x tile staging (verified r6 layout: reader-linear + XOR swizzle)
    const int nrow = wave * 16 + (lane >> 2);
    const int koff = (lane & 3) * 8;
    const int l_t = ((lane & 3) << 4) | (lane >> 2);
    const int qw = l_t ^ ((l_t >> 4) << 1);
    auto loadX = [&](int n0, float4* v) {
        int nn = n0 + nrow; if (nn >= N) nn = N - 1;
        const float* src = x + (size_t)nn * 256 + koff;
#pragma unroll
        for (int i = 0; i < 8; ++i) {
            v[2 * i]     = *reinterpret_cast<const float4*>(src + i * 32);
            v[2 * i + 1] = *reinterpret_cast<const float4*>(src + i * 32 + 4);
        }
    };
    auto writeX = [&](int buf, const float4* v) {
        u16* dst = &xb[buf][wave * 512 + qw * 8];
#pragma unroll
        for (int i = 0; i < 8; ++i) {
            u16x8 o;
            o[0] = f2bf(v[2*i].x);   o[1] = f2bf(v[2*i].y);
            o[2] = f2bf(v[2*i].z);   o[3] = f2bf(v[2*i].w);
            o[4] = f2bf(v[2*i+1].x); o[5] = f2bf(v[2*i+1].y);
            o[6] = f2bf(v[2*i+1].z); o[7] = f2bf(v[2*i+1].w);
            *reinterpret_cast<u16x8*>(dst + i * 2048) = o;
        }
    };

    const int qr = lane ^ ((lane >> 4) << 1);
    const int nt = min(8, (N - c0 + 63) >> 6);   // tiles in this chunk

    float4 v[16];
    loadX(c0, v);
    writeX(0, v);
    __syncthreads();

    for (int tt = 0; tt < nt; ++tt) {
        const int cur = tt & 1;
        const int n0 = c0 + tt * 64;
        if (tt + 1 < nt) loadX(n0 + 64, v);      // prefetch: latency under MFMA

        f32x4 acc[2][4] = {};
        const u16* xrd = &xb[cur][qr * 8];
#pragma unroll
        for (int ks = 0; ks < 8; ++ks) {
            bf16x8 b[4];
#pragma unroll
            for (int nf = 0; nf < 4; ++nf)
                b[nf] = *reinterpret_cast<const bf16x8*>(xrd + (ks * 4 + nf) * 512);
#pragma unroll
            for (int fr = 0; fr < 2; ++fr)
#pragma unroll
                for (int nf = 0; nf < 4; ++nf)
                    acc[fr][nf] = __builtin_amdgcn_mfma_f32_16x16x32_bf16(
                        a[fr][ks], b[nf], acc[fr][nf], 0, 0, 0);
        }

        // ---- partial epilogue over this wave's 32 rows ----
        float p[4];
#pragma unroll
        for (int nf = 0; nf < 4; ++nf) {
            float pp = 0.f;
#pragma unroll
            for (int fr = 0; fr < 2; ++fr) {
                f32x4 c = acc[fr][nf];
                pp += fmaxf(c[0] + b1v[fr].x, 0.f) * w2v[fr].x
                    + fmaxf(c[1] + b1v[fr].y, 0.f) * w2v[fr].y
                    + fmaxf(c[2] + b1v[fr].z, 0.f) * w2v[fr].z
                    + fmaxf(c[3] + b1v[fr].w, 0.f) * w2v[fr].w;
            }
            pp += __shfl_xor(pp, 16, 64);
            pp += __shfl_xor(pp, 32, 64);
            p[nf] = pp;
        }
        if (lane < 16) {
#pragma unroll
            for (int nf = 0; nf < 4; ++nf) pr[cur][wave][nf][l15] = p[nf];
        }
        if (tt + 1 < nt) writeX(cur ^ 1, v);     // convert+store next tile
        __syncthreads();
        // ---- cross-wave reduce + store (wave handles nf == wave) ----
        if (lane < 16) {
            float s = pr[cur][0][wave][l15] + pr[cur][1][wave][l15]
                    + pr[cur][2][wave][l15] + pr[cur][3][wave][l15];
            int n = n0 + wave * 16 + l15;
            if (n < N) scores[(size_t)n * 4 + h] = s + b2v;
        }
    }
}

// ---------- kernel 2: starts[g] = lower_bound(seg, g), g = 0..G ----------
__device__ __forceinline__ int lower_bound(const int* __restrict__ a, int n, int v) {
    int lo = 0, hi = n;
    while (lo < hi) {
        int mid = (lo + hi) >> 1;
        if (a[mid] < v) lo = mid + 1; else hi = mid;
    }
    return lo;
}

__global__ __launch_bounds__(256) void starts_kernel(
        const int* __restrict__ seg, int* __restrict__ starts, int N, int G) {
    int g = blockIdx.x * 256 + threadIdx.x;
    if (g > G) return;
    if (g == 0)      starts[0] = 0;
    else if (g == G) starts[G] = N;
    else             starts[g] = lower_bound(seg, N, g);
}

// ---------- kernel 3: fused per-graph softmax + weighted sum ----------
__global__ __launch_bounds__(512) void pool_kernel(
        const float* __restrict__ x, const float4* __restrict__ scores4,
        const int* __restrict__ starts, float* __restrict__ out) {
    __shared__ float4 red[8];
    __shared__ float wl[1024];
    __shared__ float partial[512];
    const int g = blockIdx.x;
    const int t = threadIdx.x;
    const int lane = t & 63;
    const int wv = t >> 6;
    const int start = starts[g];
    const int end = starts[g + 1];
    const int len = end - start;

    float* og = out + (size_t)g * 256;
    if (len == 0) { if (t < 256) og[t] = 0.f; return; }   // uniform across block

    // ---- pass 1: per-head max ----
    float4 mx = make_float4(-3.4e38f, -3.4e38f, -3.4e38f, -3.4e38f);
    for (int i = start + t; i < end; i += 512) {
        float4 s = scores4[i];
        mx.x = fmaxf(mx.x, s.x); mx.y = fmaxf(mx.y, s.y);
        mx.z = fmaxf(mx.z, s.z); mx.w = fmaxf(mx.w, s.w);
    }
#pragma unroll
    for (int off = 1; off < 64; off <<= 1) {
        mx.x = fmaxf(mx.x, __shfl_xor(mx.x, off, 64));
        mx.y = fmaxf(mx.y, __shfl_xor(mx.y, off, 64));
        mx.z = fmaxf(mx.z, __shfl_xor(mx.z, off, 64));
        mx.w = fmaxf(mx.w, __shfl_xor(mx.w, off, 64));
    }
    if (lane == 0) red[wv] = mx;
    __syncthreads();
    {
        float4 r = red[0];
        mx = r;
#pragma unroll
        for (int w = 1; w < 8; ++w) {
            float4 q = red[w];
            mx.x = fmaxf(mx.x, q.x); mx.y = fmaxf(mx.y, q.y);
            mx.z = fmaxf(mx.z, q.z); mx.w = fmaxf(mx.w, q.w);
        }
    }
    __syncthreads();    // red reuse

    // ---- pass 2: per-head sum(exp) ----
    float4 sm = make_float4(0.f, 0.f, 0.f, 0.f);
    for (int i = start + t; i < end; i += 512) {
        float4 s = scores4[i];
        sm.x += expf(s.x - mx.x); sm.y += expf(s.y - mx.y);
        sm.z += expf(s.z - mx.z); sm.w += expf(s.w - mx.w);
    }
#pragma unroll
    for (int off = 1; off < 64; off <<= 1) {
        sm.x += __shfl_xor(sm.x, off, 64);
        sm.y += __shfl_xor(sm.y, off, 64);
        sm.z += __shfl_xor(sm.z, off, 64);
        sm.w += __shfl_xor(sm.w, off, 64);
    }
    if (lane == 0) red[wv] = sm;
    __syncthreads();
    float4 inv;
    {
        float4 s0 = red[0];
#pragma unroll
        for (int w = 1; w < 8; ++w) {
            float4 q = red[w];
            s0.x += q.x; s0.y += q.y; s0.z += q.z; s0.w += q.w;
        }
        inv.x = 1.f / s0.x; inv.y = 1.f / s0.y;
        inv.z = 1.f / s0.z; inv.w = 1.f / s0.w;
    }

    // ---- pass 3: chunked weights + weighted sum; 2 threads per column ----
    const int col = t & 255;
    const int hf = t >> 8;          // 0: even 8-stripes, 1: odd 8-stripes
    float acc = 0.f;
    for (int c = 0; c < len; c += 1024) {
        const int cl = min(1024, len - c);
        __syncthreads();            // previous chunk's wl readers done
        for (int i = t; i < cl; i += 512) {
            float4 s = scores4[start + c + i];
            wl[i] = 0.25f * (expf(s.x - mx.x) * inv.x + expf(s.y - mx.y) * inv.y +
                             expf(s.z - mx.z) * inv.z + expf(s.w - mx.w) * inv.w);
        }
        __syncthreads();
        const float* xp = x + (size_t)(start + c) * 256 + col;
        int jb = hf * 8;
        for (; jb + 8 <= cl; jb += 16) {
            float xv[8];
#pragma unroll
            for (int jj = 0; jj < 8; ++jj) xv[jj] = xp[(size_t)(jb + jj) * 256];
#pragma unroll
            for (int jj = 0; jj < 8; ++jj) acc += wl[jb + jj] * xv[jj];
        }
        if (jb < cl) {
            const int je = min(jb + 8, cl);
            for (int j = jb; j < je; ++j) acc += wl[j] * xp[(size_t)j * 256];
        }
    }
    partial[t] = acc;
    __syncthreads();
    if (t < 256) og[t] = partial[t] + partial[t + 256];
}

extern "C" void kernel_launch(void* const* d_in, const int* in_sizes, int n_in,
                              void* d_out, int out_size, void* d_ws, size_t ws_size,
                              hipStream_t stream) {
    const float* x  = (const float*)d_in[0];
    const int* seg  = (const int*)d_in[1];
    // d_in[2] = num_graphs scalar (G=1024, fixed by problem)
    const float* W1 = (const float*)d_in[3];
    const float* b1 = (const float*)d_in[4];
    const float* W2 = (const float*)d_in[5];
    const float* b2 = (const float*)d_in[6];
    float* out = (float*)d_out;

    const int N = in_sizes[0] / 256;     // 200000
    const int G = 1024;

    char* ws = (char*)d_ws;
    float* scores = (float*)ws;                                  // N*4 fp32 = 3.2 MB
    u16* W1T      = (u16*)(ws + (size_t)N * 16);                 // 131072 u16 = 256 KB
    int* starts   = (int*)(ws + (size_t)N * 16 + 262144);        // (G+1) int

    const int chunks = (N + 511) / 512;  // 391
    transpose_w1<<<16, 256, 0, stream>>>(W1, W1T);
    starts_kernel<<<(G + 256) / 256, 256, 0, stream>>>(seg, starts, N, G);
    score_kernel<<<chunks * 4, 256, 0, stream>>>(x, W1T, b1, W2, b2, scores, N);
    pool_kernel<<<G, 512, 0, stream>>>(x, (const float4*)scores, starts, out);
}